// Round 6
// baseline (282.919 us; speedup 1.0000x reference)
//
#include <hip/hip_runtime.h>
#include <cstdint>
#include <cstddef>

// LSTM cell: B=16384, IN=HID=512.
// R6 = R5 layouts (frag-major A/W, gate-interleaved epilogue, XCD swizzle)
// with the GEMM K-loop rebuilt for TLP instead of ILP: single-buffered
// fragments + rolling loop + __launch_bounds__(256,4) -> ~112 unified regs
// -> 4 waves/SIMD (vs 2). Latency is hidden by wave interleave, not by
// register prefetch buffers (which capped occupancy at 2 waves/SIMD in R5).

#define BATCH 16384
#define KDIM  1024
#define NPK   2048
#define HIDN  512
#define NKT   32      // K tiles of 32

typedef __bf16 bf16x8 __attribute__((ext_vector_type(8)));
typedef float  f32x4  __attribute__((ext_vector_type(4)));

__device__ __forceinline__ unsigned short f2bf(float f) {
  unsigned int u = __builtin_bit_cast(unsigned int, f);
  u += 0x7fffu + ((u >> 16) & 1u);   // RNE
  return (unsigned short)(u >> 16);
}

__device__ __forceinline__ float fast_sigmoid(float x) {
  return __builtin_amdgcn_rcpf(1.0f + __expf(-x));
}
__device__ __forceinline__ float fast_tanh(float x) {
  return 1.0f - 2.0f * __builtin_amdgcn_rcpf(1.0f + __expf(2.0f * x));
}

// ---------------- prep kernels ----------------
// A frag-major: chunk index c = (bm*256 + kt*8 + g)*64 + lane, 8 bf16/chunk.
// Chunk holds A[row = bm*128 + g*16 + (lane&15)][col = kt*32 + (lane>>4)*8 .. +7].
__global__ __launch_bounds__(256) void pack_a2(const float* __restrict__ x,
                                               const float* __restrict__ h,
                                               unsigned short* __restrict__ A) {
  int c = blockIdx.x * 256 + threadIdx.x;
  int lane = c & 63;
  int g    = (c >> 6) & 7;
  int kt   = (c >> 9) & 31;
  int bm   = c >> 14;
  int row  = bm * 128 + g * 16 + (lane & 15);
  int col  = kt * 32 + ((lane >> 4) << 3);
  const float* src = (col < 512) ? (x + (size_t)row * 512 + col)
                                 : (h + (size_t)row * 512 + (col - 512));
  float4 lo = ((const float4*)src)[0];
  float4 hi = ((const float4*)src)[1];
  union { unsigned short s[8]; uint4 u; } o;
  o.s[0]=f2bf(lo.x); o.s[1]=f2bf(lo.y); o.s[2]=f2bf(lo.z); o.s[3]=f2bf(lo.w);
  o.s[4]=f2bf(hi.x); o.s[5]=f2bf(hi.y); o.s[6]=f2bf(hi.z); o.s[7]=f2bf(hi.w);
  ((uint4*)A)[c] = o.u;
}

struct GatePtrs {
  const float* wx[4];  // gate order: i, g, f, o  (ni == gate)
  const float* wh[4];
  const float* bx[4];
  const float* bh[4];
};

// W frag-major: chunk c = (bn*256 + kt*8 + wn*4 + ni)*64 + lane.
// Chunk holds W_gate[ni][j = bn*32 + wn*16 + (lane&15)][col = kt*32 + (lane>>4)*8 ..].
__global__ __launch_bounds__(256) void pack_w2(GatePtrs P,
                                               unsigned short* __restrict__ W,
                                               float* __restrict__ bias) {
  int c = blockIdx.x * 256 + threadIdx.x;
  int lane = c & 63;
  int ni   = (c >> 6) & 3;
  int wn   = (c >> 8) & 1;
  int kt   = (c >> 9) & 31;
  int bn   = c >> 14;
  int jl   = lane & 15;
  int j    = bn * 32 + wn * 16 + jl;
  int col  = kt * 32 + ((lane >> 4) << 3);
  const float* src = (col < 512) ? (P.wx[ni] + (size_t)j * 512 + col)
                                 : (P.wh[ni] + (size_t)j * 512 + (col - 512));
  float4 lo = ((const float4*)src)[0];
  float4 hi = ((const float4*)src)[1];
  union { unsigned short s[8]; uint4 u; } o;
  o.s[0]=f2bf(lo.x); o.s[1]=f2bf(lo.y); o.s[2]=f2bf(lo.z); o.s[3]=f2bf(lo.w);
  o.s[4]=f2bf(hi.x); o.s[5]=f2bf(hi.y); o.s[6]=f2bf(hi.z); o.s[7]=f2bf(hi.w);
  ((uint4*)W)[c] = o.u;
  if (kt == 0 && (lane >> 4) == 0)
    bias[bn * 128 + wn * 64 + ni * 16 + jl] = P.bx[ni][j] + P.bh[ni][j];
}

// ---------------- fused GEMM + LSTM epilogue (no LDS, no barriers) --------

__global__ __launch_bounds__(256, 4) void lstm_gemm(
    const bf16x8* __restrict__ Af,   // frag-major A
    const bf16x8* __restrict__ Bf,   // frag-major W
    const float* __restrict__ bias,  // [2048] packed
    const float* __restrict__ Cin,   // [16384,512]
    float* __restrict__ Hout,        // [16384,512]
    float* __restrict__ Cout) {      // [16384,512]
  const int tid  = threadIdx.x;
  const int lane = tid & 63;
  const int wv   = tid >> 6;     // 0..3
  const int wm   = wv >> 1;      // wave row (2x2)
  const int wn   = wv & 1;       // wave col

  // XCD-aware swizzle: blocks sharing bm co-locate on one XCD, adjacent slots.
  const int lin = blockIdx.x;    // 0..2047
  const int xcd = lin & 7;
  const int idx = lin >> 3;
  const int bn  = idx & 15;      // fastest within XCD: 16 bn share each A tile
  const int bmi = idx >> 4;      // 0..15
  const int bm  = bmi * 8 + xcd; // 0..127

  // frag pointers: pa[kt*512 + mi*64], pb[kt*512 + ni*64]
  const bf16x8* pa = Af + ((size_t)bm * 256 + wm * 4) * 64 + lane;
  const bf16x8* pb = Bf + ((size_t)bn * 256 + wn * 4) * 64 + lane;

  f32x4 acc[4][4] = {};

#pragma unroll 1
  for (int kt = 0; kt < NKT; ++kt) {
    bf16x8 fa[4], fb[4];
#pragma unroll
    for (int i = 0; i < 4; ++i) { fa[i] = pa[i * 64]; fb[i] = pb[i * 64]; }
    pa += 512; pb += 512;
#pragma unroll
    for (int mi = 0; mi < 4; ++mi)
#pragma unroll
      for (int ni = 0; ni < 4; ++ni)
        acc[mi][ni] = __builtin_amdgcn_mfma_f32_16x16x32_bf16(
            fa[mi], fb[ni], acc[mi][ni], 0, 0, 0);
  }

  // epilogue: ni == gate (0=i,1=g,2=f,3=o); lane's j fixed; no x-lane ops.
  const int jl = lane & 15;
  const int j  = bn * 32 + wn * 16 + jl;
  const int rbase = bm * 128 + wm * 64 + ((lane >> 4) << 2);
  float bv[4];
#pragma unroll
  for (int ni = 0; ni < 4; ++ni)
    bv[ni] = bias[bn * 128 + wn * 64 + ni * 16 + jl];

#pragma unroll
  for (int mi = 0; mi < 4; ++mi) {
#pragma unroll
    for (int r = 0; r < 4; ++r) {
      int row = rbase + mi * 16 + r;
      float iv = fast_sigmoid(acc[mi][0][r] + bv[0]);
      float gv = fast_tanh   (acc[mi][1][r] + bv[1]);
      float fv = fast_sigmoid(acc[mi][2][r] + bv[2]);
      float ov = fast_sigmoid(acc[mi][3][r] + bv[3]);
      float cold = Cin[(size_t)row * HIDN + j];
      float cnew = fv * cold + iv * gv;
      Hout[(size_t)row * HIDN + j] = ov * fast_tanh(cnew);
      Cout[(size_t)row * HIDN + j] = cnew;
    }
  }
}

// ---------------- launch ----------------

extern "C" void kernel_launch(void* const* d_in, const int* in_sizes, int n_in,
                              void* d_out, int out_size, void* d_ws, size_t ws_size,
                              hipStream_t stream) {
  const float* x   = (const float*)d_in[0];
  const float* h   = (const float*)d_in[1];
  const float* c   = (const float*)d_in[2];
  const float* Wxi = (const float*)d_in[3];  const float* bxi = (const float*)d_in[4];
  const float* Wxo = (const float*)d_in[5];  const float* bxo = (const float*)d_in[6];
  const float* Wxf = (const float*)d_in[7];  const float* bxf = (const float*)d_in[8];
  const float* Wxg = (const float*)d_in[9];  const float* bxg = (const float*)d_in[10];
  const float* Whi = (const float*)d_in[11]; const float* bhi = (const float*)d_in[12];
  const float* Who = (const float*)d_in[13]; const float* bho = (const float*)d_in[14];
  const float* Whf = (const float*)d_in[15]; const float* bhf = (const float*)d_in[16];
  const float* Whg = (const float*)d_in[17]; const float* bhg = (const float*)d_in[18];

  char* ws = (char*)d_ws;
  unsigned short* Apack = (unsigned short*)ws;                              // 32 MB
  unsigned short* Wpack = (unsigned short*)(ws + (size_t)BATCH * KDIM * 2); // 4 MB
  float* biasp = (float*)(ws + (size_t)BATCH * KDIM * 2 + (size_t)NPK * KDIM * 2);

  pack_a2<<<(BATCH * KDIM / 8) / 256, 256, 0, stream>>>(x, h, Apack);

  GatePtrs P;
  P.wx[0] = Wxi; P.wx[1] = Wxg; P.wx[2] = Wxf; P.wx[3] = Wxo;
  P.wh[0] = Whi; P.wh[1] = Whg; P.wh[2] = Whf; P.wh[3] = Who;
  P.bx[0] = bxi; P.bx[1] = bxg; P.bx[2] = bxf; P.bx[3] = bxo;
  P.bh[0] = bhi; P.bh[1] = bhg; P.bh[2] = bhf; P.bh[3] = bho;
  pack_w2<<<(NPK * KDIM / 8) / 256, 256, 0, stream>>>(P, Wpack, biasp);

  float* Hout = (float*)d_out;
  float* Cout = Hout + (size_t)BATCH * HIDN;
  lstm_gemm<<<dim3(2048), 256, 0, stream>>>((const bf16x8*)Apack,
                                            (const bf16x8*)Wpack,
                                            biasp, c, Hout, Cout);
}

// Round 7
// 258.439 us; speedup vs baseline: 1.0947x; 1.0947x over previous
//
#include <hip/hip_runtime.h>
#include <cstdint>
#include <cstddef>

// LSTM cell: B=16384, IN=HID=512.
// R7: back to LDS staging (global_load_lds, dbuf, 1 barrier/kt) but with a
// 256x128 block tile (8 waves, wave tile 64x64). Per block-kt: 24 KB VMEM
// for 1M MACs = 0.023 B/MAC -> clears the ~60 B/cy/CU vector-load wall that
// capped R4-R6 (reg-only design needed 127 B/cy). LDS-read (~127 B/cy needed
// vs ~100 budget) is the new ceiling at ~79% MFMA util.
// Gate-interleaved W packing keeps the fused LSTM epilogue lane-local.

#define BATCH 16384
#define KDIM  1024
#define NPK   2048
#define HIDN  512

#define BM 256
#define BN 128
#define BK 32
#define NKT (KDIM / BK)

typedef __bf16 bf16x8 __attribute__((ext_vector_type(8)));
typedef float  f32x4  __attribute__((ext_vector_type(4)));

__device__ __forceinline__ unsigned short f2bf(float f) {
  unsigned int u = __builtin_bit_cast(unsigned int, f);
  u += 0x7fffu + ((u >> 16) & 1u);   // RNE
  return (unsigned short)(u >> 16);
}

__device__ __forceinline__ float fast_sigmoid(float x) {
  return __builtin_amdgcn_rcpf(1.0f + __expf(-x));
}
__device__ __forceinline__ float fast_tanh(float x) {
  return 1.0f - 2.0f * __builtin_amdgcn_rcpf(1.0f + __expf(2.0f * x));
}

// async global->LDS, 16 B per lane; LDS dest = wave-uniform base + lane*16
__device__ __forceinline__ void gload_lds16(const void* gp, void* lds_wave_base) {
  auto g = (const __attribute__((address_space(1))) unsigned int*)(unsigned long long)gp;
  auto l = (__attribute__((address_space(3))) unsigned int*)
           (unsigned int)(unsigned long long)lds_wave_base;
  __builtin_amdgcn_global_load_lds(g, l, 16, 0, 0);
}

// ---------------- prep kernels ----------------
// A row-major bf16 [16384][1024] = [x|h] cast.
__global__ __launch_bounds__(256) void pack_a(const float* __restrict__ x,
                                              const float* __restrict__ h,
                                              unsigned short* __restrict__ A) {
  int c = blockIdx.x * 256 + threadIdx.x;   // chunk of 8 elements
  int idx = c << 3;
  int b = idx >> 10;          // row
  int k = idx & 1023;         // col
  const float* src = (k < 512) ? (x + (size_t)b * 512 + k)
                               : (h + (size_t)b * 512 + (k - 512));
  float4 lo = ((const float4*)src)[0];
  float4 hi = ((const float4*)src)[1];
  union { unsigned short s[8]; uint4 u; } o;
  o.s[0]=f2bf(lo.x); o.s[1]=f2bf(lo.y); o.s[2]=f2bf(lo.z); o.s[3]=f2bf(lo.w);
  o.s[4]=f2bf(hi.x); o.s[5]=f2bf(hi.y); o.s[6]=f2bf(hi.z); o.s[7]=f2bf(hi.w);
  ((uint4*)A)[c] = o.u;
}

struct GatePtrs {
  const float* wx[4];  // gate order: i, g, f, o
  const float* wh[4];
  const float* bx[4];
  const float* bh[4];
};

// W row-major bf16 [2048][1024], rows packed r = b*128 + wn*64 + gate*16 + jl,
// j = b*32 + wn*16 + jl.
__global__ __launch_bounds__(256) void pack_w(GatePtrs P,
                                              unsigned short* __restrict__ W,
                                              float* __restrict__ bias) {
  int c = blockIdx.x * 256 + threadIdx.x;   // chunk of 8, 128 chunks per row
  int r = c >> 7;
  int k = (c & 127) << 3;
  int b    = r >> 7;
  int rem  = r & 127;
  int wn   = (rem >> 6) & 1;
  int gate = (rem >> 4) & 3;
  int jl   = rem & 15;
  int j = b * 32 + wn * 16 + jl;
  const float* src = (k < 512) ? (P.wx[gate] + (size_t)j * 512 + k)
                               : (P.wh[gate] + (size_t)j * 512 + (k - 512));
  float4 lo = ((const float4*)src)[0];
  float4 hi = ((const float4*)src)[1];
  union { unsigned short s[8]; uint4 u; } o;
  o.s[0]=f2bf(lo.x); o.s[1]=f2bf(lo.y); o.s[2]=f2bf(lo.z); o.s[3]=f2bf(lo.w);
  o.s[4]=f2bf(hi.x); o.s[5]=f2bf(hi.y); o.s[6]=f2bf(hi.z); o.s[7]=f2bf(hi.w);
  ((uint4*)W)[c] = o.u;
  if ((c & 127) == 0) bias[r] = P.bx[gate][j] + P.bh[gate][j];
}

// ---------------- fused GEMM + LSTM epilogue ----------------

__global__ __launch_bounds__(512, 4) void lstm_gemm(
    const unsigned short* __restrict__ A,    // [16384,1024] bf16 row-major
    const unsigned short* __restrict__ W,    // [2048,1024] bf16 packed rows
    const float* __restrict__ bias,          // [2048] packed
    const float* __restrict__ Cin,           // [16384,512]
    float* __restrict__ Hout,                // [16384,512]
    float* __restrict__ Cout) {              // [16384,512]
  __shared__ __align__(16) unsigned short lds_a[2][BM * BK];  // 2 x 16 KB
  __shared__ __align__(16) unsigned short lds_b[2][BN * BK];  // 2 x  8 KB

  const int tid  = threadIdx.x;
  const int lane = tid & 63;
  const int wv   = tid >> 6;     // 0..7
  const int wm   = wv >> 1;      // 0..3  (wave row; 4 x 64 = 256)
  const int wn   = wv & 1;       // 0..1  (wave col; 2 x 64 = 128)

  // XCD-aware swizzle: the 16 bn-blocks sharing one bm co-locate on one XCD.
  const int lin = blockIdx.x;    // 0..1023
  const int xcd = lin & 7;
  const int idx = lin >> 3;
  const int bn  = idx & 15;      // 0..15
  const int bm  = (idx >> 4) * 8 + xcd;  // 0..63

  // staging: per wave per kt: 2 A-instrs (16 rows x 64 B each), 1 B-instr.
  const int srow = lane >> 2;            // 0..15
  const int scol = (lane & 3) << 3;      // element offset 0,8,16,24
  const unsigned short* gA0 =
      A + (size_t)(bm * 256 + wv * 32 + srow) * KDIM + scol;
  const unsigned short* gA1 = gA0 + (size_t)16 * KDIM;
  const unsigned short* gB0 =
      W + (size_t)(bn * 128 + wv * 16 + srow) * KDIM + scol;
  const int laA0 = (wv * 32) * BK;
  const int laA1 = (wv * 32 + 16) * BK;
  const int laB  = (wv * 16) * BK;

  f32x4 acc[4][4] = {};

  const int lrow = lane & 15;
  const int kg   = (lane >> 4) << 3;

  // prologue: stage tile 0 into buffer 0
  gload_lds16(gA0, &lds_a[0][laA0]);
  gload_lds16(gA1, &lds_a[0][laA1]);
  gload_lds16(gB0, &lds_b[0][laB]);
  gA0 += BK; gA1 += BK; gB0 += BK;

  for (int kt = 0; kt < NKT; ++kt) {
    const int cur = kt & 1;
    // barrier drains vmcnt -> buffer `cur` ready; all waves done with cur^1
    __syncthreads();
    if (kt < NKT - 1) {
      gload_lds16(gA0, &lds_a[cur ^ 1][laA0]);
      gload_lds16(gA1, &lds_a[cur ^ 1][laA1]);
      gload_lds16(gB0, &lds_b[cur ^ 1][laB]);
      gA0 += BK; gA1 += BK; gB0 += BK;
    }

    bf16x8 af[4], bf[4];
#pragma unroll
    for (int mi = 0; mi < 4; ++mi)
      af[mi] = *reinterpret_cast<const bf16x8*>(
          &lds_a[cur][(wm * 64 + mi * 16 + lrow) * BK + kg]);
#pragma unroll
    for (int ni = 0; ni < 4; ++ni)
      bf[ni] = *reinterpret_cast<const bf16x8*>(
          &lds_b[cur][(wn * 64 + ni * 16 + lrow) * BK + kg]);
#pragma unroll
    for (int mi = 0; mi < 4; ++mi)
#pragma unroll
      for (int ni = 0; ni < 4; ++ni)
        acc[mi][ni] = __builtin_amdgcn_mfma_f32_16x16x32_bf16(
            af[mi], bf[ni], acc[mi][ni], 0, 0, 0);
  }

  // epilogue: ni == gate (0=i,1=g,2=f,3=o); lane's j fixed; no x-lane ops.
  const int jl = lane & 15;
  const int j  = bn * 32 + wn * 16 + jl;
  const int rbase = bm * 256 + wm * 64 + ((lane >> 4) << 2);
  float bv[4];
#pragma unroll
  for (int ni = 0; ni < 4; ++ni)
    bv[ni] = bias[bn * 128 + wn * 64 + ni * 16 + jl];

#pragma unroll
  for (int mi = 0; mi < 4; ++mi) {
#pragma unroll
    for (int r = 0; r < 4; ++r) {
      int row = rbase + mi * 16 + r;
      float iv = fast_sigmoid(acc[mi][0][r] + bv[0]);
      float gv = fast_tanh   (acc[mi][1][r] + bv[1]);
      float fv = fast_sigmoid(acc[mi][2][r] + bv[2]);
      float ov = fast_sigmoid(acc[mi][3][r] + bv[3]);
      float cold = Cin[(size_t)row * HIDN + j];
      float cnew = fv * cold + iv * gv;
      Hout[(size_t)row * HIDN + j] = ov * fast_tanh(cnew);
      Cout[(size_t)row * HIDN + j] = cnew;
    }
  }
}

// ---------------- launch ----------------

extern "C" void kernel_launch(void* const* d_in, const int* in_sizes, int n_in,
                              void* d_out, int out_size, void* d_ws, size_t ws_size,
                              hipStream_t stream) {
  const float* x   = (const float*)d_in[0];
  const float* h   = (const float*)d_in[1];
  const float* c   = (const float*)d_in[2];
  const float* Wxi = (const float*)d_in[3];  const float* bxi = (const float*)d_in[4];
  const float* Wxo = (const float*)d_in[5];  const float* bxo = (const float*)d_in[6];
  const float* Wxf = (const float*)d_in[7];  const float* bxf = (const float*)d_in[8];
  const float* Wxg = (const float*)d_in[9];  const float* bxg = (const float*)d_in[10];
  const float* Whi = (const float*)d_in[11]; const float* bhi = (const float*)d_in[12];
  const float* Who = (const float*)d_in[13]; const float* bho = (const float*)d_in[14];
  const float* Whf = (const float*)d_in[15]; const float* bhf = (const float*)d_in[16];
  const float* Whg = (const float*)d_in[17]; const float* bhg = (const float*)d_in[18];

  char* ws = (char*)d_ws;
  unsigned short* Apack = (unsigned short*)ws;                              // 32 MB
  unsigned short* Wpack = (unsigned short*)(ws + (size_t)BATCH * KDIM * 2); // 4 MB
  float* biasp = (float*)(ws + (size_t)BATCH * KDIM * 2 + (size_t)NPK * KDIM * 2);

  pack_a<<<(BATCH * KDIM / 8) / 256, 256, 0, stream>>>(x, h, Apack);

  GatePtrs P;
  P.wx[0] = Wxi; P.wx[1] = Wxg; P.wx[2] = Wxf; P.wx[3] = Wxo;
  P.wh[0] = Whi; P.wh[1] = Whg; P.wh[2] = Whf; P.wh[3] = Who;
  P.bx[0] = bxi; P.bx[1] = bxg; P.bx[2] = bxf; P.bx[3] = bxo;
  P.bh[0] = bhi; P.bh[1] = bhg; P.bh[2] = bhf; P.bh[3] = bho;
  pack_w<<<(NPK * KDIM / 8) / 256, 256, 0, stream>>>(P, Wpack, biasp);

  float* Hout = (float*)d_out;
  float* Cout = Hout + (size_t)BATCH * HIDN;
  lstm_gemm<<<dim3((BATCH / BM) * (NPK / BN)), 512, 0, stream>>>(
      Apack, Wpack, biasp, c, Hout, Cout);
}